// Round 4
// baseline (729.136 us; speedup 1.0000x reference)
//
#include <hip/hip_runtime.h>
#include <hip/hip_bf16.h>

#define Sdim 4096
#define Ndim 32
#define Hdim 512
#define Mdim (Sdim * Ndim)

typedef __bf16 bf16x8 __attribute__((ext_vector_type(8)));
typedef float f32x4 __attribute__((ext_vector_type(4)));

__device__ __forceinline__ float ftanh(float x) {
    float e = __expf(2.f * x);
    return 1.f - 2.f / (e + 1.f);
}

// ---------------- bias[n][c] = hidden[n]·Ww[c] + Wb[c] + Ub[c]
__global__ __launch_bounds__(256) void k_prep_bias(
    const float* __restrict__ hidden, const float* __restrict__ Ww,
    const float* __restrict__ Wb, const float* __restrict__ Ubias,
    float* __restrict__ bias) {
    const int t = threadIdx.x, w = t >> 6, lane = t & 63;
    const int cc = blockIdx.x * 4 + w;
    const float4 w0 = *(const float4*)(Ww + (size_t)cc * Hdim + lane * 8);
    const float4 w1 = *(const float4*)(Ww + (size_t)cc * Hdim + lane * 8 + 4);
    const float wb = Wb[cc] + Ubias[cc];
    for (int n = 0; n < Ndim; ++n) {
        const float4 h0 = *(const float4*)(hidden + n * Hdim + lane * 8);
        const float4 h1 = *(const float4*)(hidden + n * Hdim + lane * 8 + 4);
        float p = w0.x * h0.x + w0.y * h0.y + w0.z * h0.z + w0.w * h0.w +
                  w1.x * h1.x + w1.y * h1.y + w1.z * h1.z + w1.w * h1.w;
        p += __shfl_xor(p, 1);  p += __shfl_xor(p, 2);
        p += __shfl_xor(p, 4);  p += __shfl_xor(p, 8);
        p += __shfl_xor(p, 16); p += __shfl_xor(p, 32);
        if (lane == 0) bias[n * Hdim + cc] = p + wb;
    }
}

// ---------------- U_w fp32 -> bf16 (packed cvt)
__global__ __launch_bounds__(256) void k_cvt(
    const float* __restrict__ src, unsigned short* __restrict__ dst) {
    const int i = blockIdx.x * 256 + threadIdx.x;
    float4 v = ((const float4*)src)[i];
    union { __hip_bfloat162 h[2]; ushort4 u; } r;
    r.h[0] = __float22bfloat162_rn(make_float2(v.x, v.y));
    r.h[1] = __float22bfloat162_rn(make_float2(v.z, v.w));
    ((ushort4*)dst)[i] = r.u;
}

// ---------------- fused partial score, NO-LDS register GEMM.
// Block: 256 thr = 4 waves, tile 64 rows x 256 cols (wave = 64x64).
// A fp32 streamed global->reg->cvt; B bf16 frags straight from L1/L2.
// Zero barriers in the K-loop -> compiler pipelines loads across steps.
__global__ __launch_bounds__(256, 3) void k_gemm_score(
    const float* __restrict__ enc,          // [M, H] fp32
    const unsigned short* __restrict__ Ub,  // [H, H] bf16, row=out col
    const float* __restrict__ bias,         // [N, H]
    const float* __restrict__ vw,           // [H]
    float* __restrict__ scorep) {           // [2][N, S] partials
    __shared__ float ssm[4][64];

    const int t = threadIdx.x;
    const int lane = t & 63;
    const int w = t >> 6;      // wave 0..3
    const int c = lane & 15;
    const int q = lane >> 4;

    const int rowblk = blockIdx.x >> 1;
    const int colblk = blockIdx.x & 1;
    const int mBase = rowblk * 64;
    const int colBase = colblk * 256 + w * 64;

    // per-lane fragment base pointers
    const float* aP[4];
    const unsigned short* bP[4];
#pragma unroll
    for (int mi = 0; mi < 4; ++mi)
        aP[mi] = enc + (size_t)(mBase + mi * 16 + c) * Hdim + q * 8;
#pragma unroll
    for (int ni = 0; ni < 4; ++ni)
        bP[ni] = Ub + (size_t)(colBase + ni * 16 + c) * Hdim + q * 8;

    f32x4 acc[4][4];
#pragma unroll
    for (int i = 0; i < 4; ++i)
#pragma unroll
        for (int j = 0; j < 4; ++j) acc[i][j] = (f32x4){0.f, 0.f, 0.f, 0.f};

#pragma unroll 2
    for (int kk = 0; kk < Hdim / 32; ++kk) {
        bf16x8 af[4], bfr[4];
#pragma unroll
        for (int mi = 0; mi < 4; ++mi) {
            const float4 f0 = *(const float4*)(aP[mi] + kk * 32);
            const float4 f1 = *(const float4*)(aP[mi] + kk * 32 + 4);
            union { __hip_bfloat162 h[4]; bf16x8 v; } pk;
            pk.h[0] = __float22bfloat162_rn(make_float2(f0.x, f0.y));
            pk.h[1] = __float22bfloat162_rn(make_float2(f0.z, f0.w));
            pk.h[2] = __float22bfloat162_rn(make_float2(f1.x, f1.y));
            pk.h[3] = __float22bfloat162_rn(make_float2(f1.z, f1.w));
            af[mi] = pk.v;
        }
#pragma unroll
        for (int ni = 0; ni < 4; ++ni)
            bfr[ni] = *(const bf16x8*)(bP[ni] + kk * 32);
#pragma unroll
        for (int mi = 0; mi < 4; ++mi)
#pragma unroll
            for (int ni = 0; ni < 4; ++ni)
                acc[mi][ni] = __builtin_amdgcn_mfma_f32_16x16x32_bf16(
                    af[mi], bfr[ni], acc[mi][ni], 0, 0, 0);
    }

    // epilogue: per-row partial of v·tanh(acc + bias)  (v_b cancels in softmax)
    float vcol[4];
#pragma unroll
    for (int ni = 0; ni < 4; ++ni) vcol[ni] = vw[colBase + ni * 16 + c];

#pragma unroll
    for (int mi = 0; mi < 4; ++mi) {
#pragma unroll
        for (int reg = 0; reg < 4; ++reg) {
            const int rl = mi * 16 + q * 4 + reg;  // row in [0,64)
            const int n = rl & 31;                 // mBase % 32 == 0
            float p = 0.f;
#pragma unroll
            for (int ni = 0; ni < 4; ++ni) {
                const int col = colBase + ni * 16 + c;
                float e = acc[mi][ni][reg] + bias[n * Hdim + col];
                p += vcol[ni] * ftanh(e);
            }
            p += __shfl_xor(p, 1);
            p += __shfl_xor(p, 2);
            p += __shfl_xor(p, 4);
            p += __shfl_xor(p, 8);
            if (c == 0) ssm[w][rl] = p;
        }
    }
    __syncthreads();
    if (t < 64) {
        const int m = mBase + t;
        const float s = ssm[0][t] + ssm[1][t] + ssm[2][t] + ssm[3][t];
        scorep[colblk * Mdim + (m & 31) * Sdim + (m >> 5)] = s;
    }
}

// ---------------- softmax over S per n; score = score0 + score1
__global__ __launch_bounds__(256) void k_softmax(
    const float* __restrict__ scorep,  // [2][N][S]
    float* __restrict__ out_w) {       // d_out+16384, [S][N]
    const int n = blockIdx.x;
    const int t = threadIdx.x;
    const int w = t >> 6;
    __shared__ float row[Sdim];
    __shared__ float red[8];
    const float4* s0 = (const float4*)(scorep + n * Sdim);
    const float4* s1 = (const float4*)(scorep + Mdim + n * Sdim);

    float mx = -1e30f;
    for (int i = t; i < Sdim / 4; i += 256) {
        float4 a = s0[i], b = s1[i];
        float4 v;
        v.x = a.x + b.x; v.y = a.y + b.y; v.z = a.z + b.z; v.w = a.w + b.w;
        ((float4*)row)[i] = v;
        mx = fmaxf(mx, fmaxf(fmaxf(v.x, v.y), fmaxf(v.z, v.w)));
    }
#pragma unroll
    for (int o = 32; o > 0; o >>= 1) mx = fmaxf(mx, __shfl_xor(mx, o));
    if ((t & 63) == 0) red[w] = mx;
    __syncthreads();
    mx = fmaxf(fmaxf(red[0], red[1]), fmaxf(red[2], red[3]));

    float sum = 0.f;
    for (int i = t; i < Sdim; i += 256) sum += __expf(row[i] - mx);
#pragma unroll
    for (int o = 32; o > 0; o >>= 1) sum += __shfl_xor(sum, o);
    if ((t & 63) == 0) red[4 + w] = sum;
    __syncthreads();
    sum = red[4] + red[5] + red[6] + red[7];
    const float inv = 1.f / sum;
    for (int i = t; i < Sdim; i += 256)
        out_w[i * Ndim + n] = __expf(row[i] - mx) * inv;
}

// ---------------- context partials: part[sc][n][h] = sum_{s in chunk} w*enc
__global__ __launch_bounds__(256) void k_context(
    const float* __restrict__ enc, const float* __restrict__ wts,  // [S][N]
    float* __restrict__ part) {
    const int n = blockIdx.x & 31;
    const int sc = blockIdx.x >> 5;  // 0..15
    const int s0 = sc * 256;
    const int t = threadIdx.x;
    const int hv = t & 127;
    const int sl = t >> 7;  // 0..1
    float4 a0 = {0.f, 0.f, 0.f, 0.f}, a1 = {0.f, 0.f, 0.f, 0.f};
    float4 a2 = {0.f, 0.f, 0.f, 0.f}, a3 = {0.f, 0.f, 0.f, 0.f};
    for (int i = sl * 4; i < 256; i += 8) {
        const float w0 = wts[(size_t)(s0 + i) * Ndim + n];
        const float w1 = wts[(size_t)(s0 + i + 1) * Ndim + n];
        const float w2 = wts[(size_t)(s0 + i + 2) * Ndim + n];
        const float w3 = wts[(size_t)(s0 + i + 3) * Ndim + n];
        const float4 e0 = *(const float4*)(enc + ((size_t)(s0 + i) * Ndim + n) * Hdim + hv * 4);
        const float4 e1 = *(const float4*)(enc + ((size_t)(s0 + i + 1) * Ndim + n) * Hdim + hv * 4);
        const float4 e2 = *(const float4*)(enc + ((size_t)(s0 + i + 2) * Ndim + n) * Hdim + hv * 4);
        const float4 e3 = *(const float4*)(enc + ((size_t)(s0 + i + 3) * Ndim + n) * Hdim + hv * 4);
        a0.x += w0 * e0.x; a0.y += w0 * e0.y; a0.z += w0 * e0.z; a0.w += w0 * e0.w;
        a1.x += w1 * e1.x; a1.y += w1 * e1.y; a1.z += w1 * e1.z; a1.w += w1 * e1.w;
        a2.x += w2 * e2.x; a2.y += w2 * e2.y; a2.z += w2 * e2.z; a2.w += w2 * e2.w;
        a3.x += w3 * e3.x; a3.y += w3 * e3.y; a3.z += w3 * e3.z; a3.w += w3 * e3.w;
    }
    a0.x += a1.x + a2.x + a3.x; a0.y += a1.y + a2.y + a3.y;
    a0.z += a1.z + a2.z + a3.z; a0.w += a1.w + a2.w + a3.w;
    __shared__ float4 red[128];
    if (sl == 1) red[hv] = a0;
    __syncthreads();
    if (sl == 0) {
        const float4 b = red[hv];
        float4 r;
        r.x = a0.x + b.x; r.y = a0.y + b.y; r.z = a0.z + b.z; r.w = a0.w + b.w;
        *(float4*)(part + (size_t)(sc * 32 + n) * Hdim + hv * 4) = r;
    }
}

// ---------------- reduce 16 partial chunks -> context [N,H]
__global__ __launch_bounds__(256) void k_ctx_reduce(
    const float* __restrict__ part, float* __restrict__ out) {
    const int j = blockIdx.x * 256 + threadIdx.x;  // float4 index, 4096 total
    float4 s = {0.f, 0.f, 0.f, 0.f};
    for (int i = 0; i < 16; ++i) {
        const float4 v = ((const float4*)part)[i * 4096 + j];
        s.x += v.x; s.y += v.y; s.z += v.z; s.w += v.w;
    }
    ((float4*)out)[j] = s;
}

extern "C" void kernel_launch(void* const* d_in, const int* in_sizes, int n_in,
                              void* d_out, int out_size, void* d_ws,
                              size_t ws_size, hipStream_t stream) {
    const float* hidden = (const float*)d_in[0];
    const float* enc    = (const float*)d_in[1];
    const float* Ww     = (const float*)d_in[2];
    const float* Wb     = (const float*)d_in[3];
    const float* Uw     = (const float*)d_in[4];
    const float* Ubias  = (const float*)d_in[5];
    const float* vw     = (const float*)d_in[6];

    float* out = (float*)d_out;  // [0,16384): context; [16384,...): weights [S,N]

    char* ws = (char*)d_ws;
    float* bias          = (float*)(ws);                        // 64 KB
    unsigned short* Ub16 = (unsigned short*)(ws + (64 << 10));  // 512 KB
    float* scorep        = (float*)(ws + (576 << 10));          // 2x512 KB
    // part aliases [64K,1088K): Ub16 + scorep[0] dead after softmax
    float* part          = (float*)(ws + (64 << 10));           // 1 MB

    k_prep_bias<<<128, 256, 0, stream>>>(hidden, Ww, Wb, Ubias, bias);
    k_cvt<<<256, 256, 0, stream>>>(Uw, Ub16);
    k_gemm_score<<<(Mdim / 64) * 2, 256, 0, stream>>>(enc, Ub16, bias, vw,
                                                      scorep);
    k_softmax<<<Ndim, 256, 0, stream>>>(scorep, out + Ndim * Hdim);
    k_context<<<Ndim * (Sdim / 256), 256, 0, stream>>>(enc, out + Ndim * Hdim,
                                                       part);
    k_ctx_reduce<<<16, 256, 0, stream>>>(part, out);
}

// Round 5
// 593.558 us; speedup vs baseline: 1.2284x; 1.2284x over previous
//
#include <hip/hip_runtime.h>
#include <hip/hip_bf16.h>

#define Sdim 4096
#define Ndim 32
#define Hdim 512
#define Mdim (Sdim * 32)

typedef __bf16 bf16x8 __attribute__((ext_vector_type(8)));
typedef float f32x4 __attribute__((ext_vector_type(4)));

__device__ __forceinline__ void load_lds16(const void* g, void* l) {
    __builtin_amdgcn_global_load_lds(
        (const __attribute__((address_space(1))) void*)g,
        (__attribute__((address_space(3))) void*)l, 16, 0, 0);
}

__device__ __forceinline__ float ftanh(float x) {
    float e = __expf(2.f * x);
    return 1.f - 2.f / (e + 1.f);
}

// ---------------- bias_t[c][n] = hidden[n]·Ww[c] + Wb[c] + Ub[c]
__global__ __launch_bounds__(256) void k_prep_bias(
    const float* __restrict__ hidden, const float* __restrict__ Ww,
    const float* __restrict__ Wb, const float* __restrict__ Ubias,
    float* __restrict__ bias_t) {  // [H][N]
    const int t = threadIdx.x, w = t >> 6, lane = t & 63;
    const int cc = blockIdx.x * 4 + w;
    const float4 w0 = *(const float4*)(Ww + (size_t)cc * Hdim + lane * 8);
    const float4 w1 = *(const float4*)(Ww + (size_t)cc * Hdim + lane * 8 + 4);
    const float wb = Wb[cc] + Ubias[cc];
    for (int n = 0; n < Ndim; ++n) {
        const float4 h0 = *(const float4*)(hidden + n * Hdim + lane * 8);
        const float4 h1 = *(const float4*)(hidden + n * Hdim + lane * 8 + 4);
        float p = w0.x * h0.x + w0.y * h0.y + w0.z * h0.z + w0.w * h0.w +
                  w1.x * h1.x + w1.y * h1.y + w1.z * h1.z + w1.w * h1.w;
        p += __shfl_xor(p, 1);  p += __shfl_xor(p, 2);
        p += __shfl_xor(p, 4);  p += __shfl_xor(p, 8);
        p += __shfl_xor(p, 16); p += __shfl_xor(p, 32);
        if (lane == 0) bias_t[cc * Ndim + n] = p + wb;
    }
}

// ---------------- U_w fp32 -> bf16
__global__ __launch_bounds__(256) void k_cvt(
    const float* __restrict__ src, unsigned short* __restrict__ dst) {
    const int i = blockIdx.x * 256 + threadIdx.x;
    float4 v = ((const float4*)src)[i];
    union { __hip_bfloat162 h[2]; ushort4 u; } r;
    r.h[0] = __float22bfloat162_rn(make_float2(v.x, v.y));
    r.h[1] = __float22bfloat162_rn(make_float2(v.z, v.w));
    ((ushort4*)dst)[i] = r.u;
}

// ---------------- fused partial score. Tile 64M x 256N x BK=64, 4 waves,
// wave = 64x64. A: fp32 global->reg (prefetched across kk)->cvt->LDS (144B
// rows: 2-way banks, free). B: global_load_lds, chunk^row XOR swizzle
// (2-way on read, free). 8 K-steps. Epilogue fuses tanh + v-dot.
__global__ __launch_bounds__(256, 3) void k_gemm_score(
    const float* __restrict__ enc,          // [M, H] fp32
    const unsigned short* __restrict__ Ub,  // [H, H] bf16
    const float* __restrict__ bias_t,       // [H][N]
    const float* __restrict__ vw,           // [H]
    float* __restrict__ scorep) {           // [2][N][S] partials
    __shared__ __align__(16) unsigned short Asm[64 * 72];   // 144 B rows
    __shared__ __align__(16) unsigned short Bsm[256 * 64];  // 32 KB, swizzled
    __shared__ float ssm[4][64];

    const int t = threadIdx.x;
    const int lane = t & 63;
    const int w = t >> 6;   // wave 0..3 -> col strip w*64
    const int c = lane & 15;
    const int q = lane >> 4;

    const int rowblk = blockIdx.x >> 1;
    const int colblk = blockIdx.x & 1;
    const int mBase = rowblk * 64;
    const int colBase = colblk * 256;

    // A staging: thread -> row t>>2, 16-float chunk t&3
    const int ar = t >> 2;
    const int aq = t & 3;
    const float* aptr = enc + (size_t)(mBase + ar) * Hdim + aq * 16;
    unsigned short* awr = &Asm[ar * 72 + aq * 16];

    // B staging: 8 DMA issues; lane covers row lane>>3, fetches global chunk
    // (lane&7)^(row&7) so LDS slot s holds global chunk s^row.
    const int brow = lane >> 3;
    const int gchunk = (lane & 7) ^ (brow & 7);
    const unsigned short* bptr[8];
    unsigned short* bdst[8];
#pragma unroll
    for (int j = 0; j < 8; ++j) {
        const int r0 = w * 64 + j * 8;
        bptr[j] = Ub + (size_t)(colBase + r0 + brow) * Hdim + gchunk * 8;
        bdst[j] = &Bsm[r0 * 64];
    }

    f32x4 acc[4][4];
#pragma unroll
    for (int i = 0; i < 4; ++i)
#pragma unroll
        for (int j = 0; j < 4; ++j) acc[i][j] = (f32x4){0.f, 0.f, 0.f, 0.f};

    float4 pa0 = *(const float4*)(aptr + 0);
    float4 pa1 = *(const float4*)(aptr + 4);
    float4 pa2 = *(const float4*)(aptr + 8);
    float4 pa3 = *(const float4*)(aptr + 12);

#pragma unroll
    for (int kk = 0; kk < 8; ++kk) {
        __syncthreads();  // LDS free (prev frag reads done)
        union { __hip_bfloat162 h[4]; bf16x8 v; } p0, p1;
        p0.h[0] = __float22bfloat162_rn(make_float2(pa0.x, pa0.y));
        p0.h[1] = __float22bfloat162_rn(make_float2(pa0.z, pa0.w));
        p0.h[2] = __float22bfloat162_rn(make_float2(pa1.x, pa1.y));
        p0.h[3] = __float22bfloat162_rn(make_float2(pa1.z, pa1.w));
        p1.h[0] = __float22bfloat162_rn(make_float2(pa2.x, pa2.y));
        p1.h[1] = __float22bfloat162_rn(make_float2(pa2.z, pa2.w));
        p1.h[2] = __float22bfloat162_rn(make_float2(pa3.x, pa3.y));
        p1.h[3] = __float22bfloat162_rn(make_float2(pa3.z, pa3.w));
        *(bf16x8*)(awr) = p0.v;
        *(bf16x8*)(awr + 8) = p1.v;
#pragma unroll
        for (int j = 0; j < 8; ++j)
            load_lds16(bptr[j] + kk * 64, bdst[j]);
        __syncthreads();  // staging visible (vmcnt+lgkm drain)
        if (kk < 7) {     // prefetch next A AFTER the drain: MFMA covers it
            pa0 = *(const float4*)(aptr + (kk + 1) * 64);
            pa1 = *(const float4*)(aptr + (kk + 1) * 64 + 4);
            pa2 = *(const float4*)(aptr + (kk + 1) * 64 + 8);
            pa3 = *(const float4*)(aptr + (kk + 1) * 64 + 12);
        }
#pragma unroll
        for (int kh = 0; kh < 2; ++kh) {
            bf16x8 af[4], bfr[4];
#pragma unroll
            for (int mi = 0; mi < 4; ++mi)
                af[mi] = *(const bf16x8*)&Asm[(mi * 16 + c) * 72 + kh * 32 + q * 8];
#pragma unroll
            for (int ni = 0; ni < 4; ++ni) {
                const int r = w * 64 + ni * 16 + c;
                const int slot = (kh * 4 + q) ^ (c & 7);
                bfr[ni] = *(const bf16x8*)&Bsm[r * 64 + slot * 8];
            }
#pragma unroll
            for (int mi = 0; mi < 4; ++mi)
#pragma unroll
                for (int ni = 0; ni < 4; ++ni)
                    acc[mi][ni] = __builtin_amdgcn_mfma_f32_16x16x32_bf16(
                        af[mi], bfr[ni], acc[mi][ni], 0, 0, 0);
        }
    }

    // epilogue: partial score = sum_col v[col]*tanh(acc + bias)  (v_b cancels)
    float vcol[4];
#pragma unroll
    for (int ni = 0; ni < 4; ++ni)
        vcol[ni] = vw[colBase + w * 64 + ni * 16 + c];

#pragma unroll
    for (int mi = 0; mi < 4; ++mi) {
#pragma unroll
        for (int reg = 0; reg < 4; ++reg) {
            const int rl = mi * 16 + q * 4 + reg;  // row 0..63
            const int n = rl & 31;                 // mBase % 64 == 0
            float p = 0.f;
#pragma unroll
            for (int ni = 0; ni < 4; ++ni) {
                const int col = colBase + w * 64 + ni * 16 + c;
                float e = acc[mi][ni][reg] + bias_t[col * Ndim + n];
                p += vcol[ni] * ftanh(e);
            }
            p += __shfl_xor(p, 1);
            p += __shfl_xor(p, 2);
            p += __shfl_xor(p, 4);
            p += __shfl_xor(p, 8);
            if (c == 0) ssm[w][rl] = p;
        }
    }
    __syncthreads();
    if (t < 64) {
        const int m = mBase + t;
        const float s = ssm[0][t] + ssm[1][t] + ssm[2][t] + ssm[3][t];
        scorep[colblk * Mdim + (m & 31) * Sdim + (m >> 5)] = s;
    }
}

// ---------------- softmax over S per n; coalesced write to wts [N][S]
__global__ __launch_bounds__(256) void k_softmax(
    const float* __restrict__ scorep,  // [2][N][S]
    float* __restrict__ wts) {         // [N][S]
    const int n = blockIdx.x;
    const int t = threadIdx.x;
    const int w = t >> 6;
    __shared__ float row[Sdim];
    __shared__ float red[8];
    const float4* s0 = (const float4*)(scorep + n * Sdim);
    const float4* s1 = (const float4*)(scorep + Mdim + n * Sdim);

    float mx = -1e30f;
    for (int i = t; i < Sdim / 4; i += 256) {
        float4 a = s0[i], b = s1[i];
        float4 v;
        v.x = a.x + b.x; v.y = a.y + b.y; v.z = a.z + b.z; v.w = a.w + b.w;
        ((float4*)row)[i] = v;
        mx = fmaxf(mx, fmaxf(fmaxf(v.x, v.y), fmaxf(v.z, v.w)));
    }
#pragma unroll
    for (int o = 32; o > 0; o >>= 1) mx = fmaxf(mx, __shfl_xor(mx, o));
    if ((t & 63) == 0) red[w] = mx;
    __syncthreads();
    mx = fmaxf(fmaxf(red[0], red[1]), fmaxf(red[2], red[3]));

    float sum = 0.f;
    for (int i = t; i < Sdim; i += 256) sum += __expf(row[i] - mx);
#pragma unroll
    for (int o = 32; o > 0; o >>= 1) sum += __shfl_xor(sum, o);
    if ((t & 63) == 0) red[4 + w] = sum;
    __syncthreads();
    sum = red[4] + red[5] + red[6] + red[7];
    const float inv = 1.f / sum;
    for (int i = t; i < Sdim; i += 256)
        wts[n * Sdim + i] = __expf(row[i] - mx) * inv;
}

// ---------------- wts [N][S] -> out_w [S][N] (coalesced both sides via LDS)
__global__ __launch_bounds__(256) void k_transpose(
    const float* __restrict__ wts, float* __restrict__ out_w) {
    __shared__ float tl[Ndim][129];
    const int s0 = blockIdx.x * 128;
    const int t = threadIdx.x;
    const int rr = t >> 3, cb = (t & 7) * 4;
#pragma unroll
    for (int j = 0; j < 4; ++j)
        *(float4*)&tl[rr][cb + j * 32] =
            *(const float4*)(wts + (size_t)rr * Sdim + s0 + cb + j * 32);
    __syncthreads();
    const int sl = t >> 1, nb = (t & 1) * 16;
#pragma unroll
    for (int j = 0; j < 4; ++j) {
        const int n0 = nb + j * 4;
        float4 v;
        v.x = tl[n0][sl]; v.y = tl[n0 + 1][sl];
        v.z = tl[n0 + 2][sl]; v.w = tl[n0 + 3][sl];
        *(float4*)(out_w + (size_t)(s0 + sl) * Ndim + n0) = v;
    }
}

// ---------------- context partials: part[sc][n][h] over 128-s chunks
__global__ __launch_bounds__(256) void k_context(
    const float* __restrict__ enc, const float* __restrict__ wts,  // [N][S]
    float* __restrict__ part) {
    const int n = blockIdx.x & 31;
    const int sc = blockIdx.x >> 5;  // 0..31
    const int s0 = sc * 128;
    const int t = threadIdx.x;
    const int hv = t & 127;
    const int sl = t >> 7;  // 0..1
    const float* wrow = wts + (size_t)n * Sdim + s0;
    float4 a0 = {0, 0, 0, 0}, a1 = {0, 0, 0, 0};
    float4 a2 = {0, 0, 0, 0}, a3 = {0, 0, 0, 0};
    for (int i = sl * 4; i < 128; i += 8) {
        const float w0 = wrow[i], w1 = wrow[i + 1];
        const float w2 = wrow[i + 2], w3 = wrow[i + 3];
        const float4 e0 = *(const float4*)(enc + ((size_t)(s0 + i) * Ndim + n) * Hdim + hv * 4);
        const float4 e1 = *(const float4*)(enc + ((size_t)(s0 + i + 1) * Ndim + n) * Hdim + hv * 4);
        const float4 e2 = *(const float4*)(enc + ((size_t)(s0 + i + 2) * Ndim + n) * Hdim + hv * 4);
        const float4 e3 = *(const float4*)(enc + ((size_t)(s0 + i + 3) * Ndim + n) * Hdim + hv * 4);
        a0.x += w0 * e0.x; a0.y += w0 * e0.y; a0.z += w0 * e0.z; a0.w += w0 * e0.w;
        a1.x += w1 * e1.x; a1.y += w1 * e1.y; a1.z += w1 * e1.z; a1.w += w1 * e1.w;
        a2.x += w2 * e2.x; a2.y += w2 * e2.y; a2.z += w2 * e2.z; a2.w += w2 * e2.w;
        a3.x += w3 * e3.x; a3.y += w3 * e3.y; a3.z += w3 * e3.z; a3.w += w3 * e3.w;
    }
    a0.x += a1.x + a2.x + a3.x; a0.y += a1.y + a2.y + a3.y;
    a0.z += a1.z + a2.z + a3.z; a0.w += a1.w + a2.w + a3.w;
    __shared__ float4 red[128];
    if (sl == 1) red[hv] = a0;
    __syncthreads();
    if (sl == 0) {
        const float4 b = red[hv];
        float4 r;
        r.x = a0.x + b.x; r.y = a0.y + b.y; r.z = a0.z + b.z; r.w = a0.w + b.w;
        *(float4*)(part + (size_t)(sc * 32 + n) * Hdim + hv * 4) = r;
    }
}

// ---------------- reduce 32 partial chunks -> context [N,H]
__global__ __launch_bounds__(256) void k_ctx_reduce(
    const float* __restrict__ part, float* __restrict__ out) {
    const int j = blockIdx.x * 256 + threadIdx.x;  // float4 idx, 4096 total
    float4 s = {0, 0, 0, 0};
    for (int i = 0; i < 32; ++i) {
        const float4 v = ((const float4*)part)[i * 4096 + j];
        s.x += v.x; s.y += v.y; s.z += v.z; s.w += v.w;
    }
    ((float4*)out)[j] = s;
}

extern "C" void kernel_launch(void* const* d_in, const int* in_sizes, int n_in,
                              void* d_out, int out_size, void* d_ws,
                              size_t ws_size, hipStream_t stream) {
    const float* hidden = (const float*)d_in[0];
    const float* enc    = (const float*)d_in[1];
    const float* Ww     = (const float*)d_in[2];
    const float* Wb     = (const float*)d_in[3];
    const float* Uw     = (const float*)d_in[4];
    const float* Ubias  = (const float*)d_in[5];
    const float* vw     = (const float*)d_in[6];

    float* out = (float*)d_out;  // [0,16384): context; rest: weights [S][N]

    char* ws = (char*)d_ws;
    float* wts           = (float*)(ws);                         // 512 KB
    unsigned short* Ub16 = (unsigned short*)(ws + (512 << 10));  // 512 KB
    float* scorep        = (float*)(ws + (1024 << 10));          // 1 MB
    float* bias_t        = (float*)(ws + (2048 << 10));          // 64 KB
    // part aliases [512K,2560K): Ub16/scorep/bias_t all dead by k_context
    float* part          = (float*)(ws + (512 << 10));           // 2 MB

    k_prep_bias<<<128, 256, 0, stream>>>(hidden, Ww, Wb, Ubias, bias_t);
    k_cvt<<<256, 256, 0, stream>>>(Uw, Ub16);
    k_gemm_score<<<(Mdim / 64) * 2, 256, 0, stream>>>(enc, Ub16, bias_t, vw,
                                                      scorep);
    k_softmax<<<Ndim, 256, 0, stream>>>(scorep, wts);
    k_transpose<<<Sdim / 128, 256, 0, stream>>>(wts, out + Ndim * Hdim);
    k_context<<<Ndim * (Sdim / 128), 256, 0, stream>>>(enc, wts, part);
    k_ctx_reduce<<<16, 256, 0, stream>>>(part, out);
}